// Round 1
// baseline (1264.022 us; speedup 1.0000x reference)
//
#include <hip/hip_runtime.h>
#include <math.h>

// Problem constants (from reference): N=500000 samples, D=256 features, C=100 classes.
#define NCLASS 100
#define DIM    256

// Pass-1 tiling: 4 column-groups of 64 columns, 128 sample chunks.
#define COLS      64
#define NCG       (DIM / COLS)   // 4
#define SCHUNKS   128
#define BLOCK     256            // 4 waves

// Workspace layout (floats), ws assumed >= ~206 KB:
//   [0, C*D)              class sums
//   [C*D, C*D + C)        class counts (float)
//   C*D + C               is64 flag (int)
//   C*D + C + 4 .. +C*D   centers (16B-aligned: 25704 % 4 == 0)
#define WS_SUMS    0
#define WS_COUNTS  (NCLASS * DIM)                  // 25600
#define WS_FLAG    (NCLASS * DIM + NCLASS)         // 25700
#define WS_CENTERS (NCLASS * DIM + NCLASS + 4)     // 25704 (float4-aligned)

#define ZERO_BLOCKS ((NCLASS * DIM + NCLASS + BLOCK - 1) / BLOCK)  // 101

// Read label i, handling both int32 and int64 (little-endian low word) layouts.
__device__ __forceinline__ int load_label(const unsigned int* lab, int i, int is64) {
    int v = is64 ? (int)lab[2 * i] : (int)lab[i];
    // clamp for memory safety (labels are in [0,100) per reference)
    return min(max(v, 0), NCLASS - 1);
}

// Kernel 0: zero sums+counts; last block detects label dtype.
__global__ __launch_bounds__(BLOCK) void k0_init(float* __restrict__ zero_region,
                                                 int* __restrict__ flag,
                                                 const unsigned int* __restrict__ lab,
                                                 int n) {
    int b = blockIdx.x, t = threadIdx.x;
    if (b < ZERO_BLOCKS) {
        int idx = b * BLOCK + t;
        if (idx < NCLASS * DIM + NCLASS) zero_region[idx] = 0.0f;
    } else {
        // dtype detection: int64 labels (<100) have zero high words at odd int32 slots.
        __shared__ unsigned int any_nonzero;
        if (t == 0) any_nonzero = 0u;
        __syncthreads();
        unsigned int v = 0u;
        int limit = min(1024, (n - 1) / 2);
        for (int i = t; i < limit; i += BLOCK) v |= lab[2 * i + 1];
        if (v) atomicOr(&any_nonzero, 1u);
        __syncthreads();
        if (t == 0) *flag = (any_nonzero == 0u) ? 1 : 0;  // 1 => int64 layout
    }
}

// Kernel 1: accumulate class sums (LDS histogram) + counts.
__global__ __launch_bounds__(BLOCK) void k1_accum(const float* __restrict__ feat,
                                                  const unsigned int* __restrict__ lab,
                                                  const int* __restrict__ flag,
                                                  float* __restrict__ sums,
                                                  float* __restrict__ counts,
                                                  int n) {
    __shared__ float lsum[NCLASS * COLS];  // 25.6 KB
    __shared__ float lcnt[NCLASS];

    int t = threadIdx.x;
    int lane = t & 63;
    int w = t >> 6;                  // wave 0..3
    bool doCnt = (blockIdx.y == 0);  // only one column-group counts

    for (int i = t; i < NCLASS * COLS; i += BLOCK) lsum[i] = 0.0f;
    if (doCnt) for (int i = t; i < NCLASS; i += BLOCK) lcnt[i] = 0.0f;
    __syncthreads();

    int is64 = *flag;
    int d0 = blockIdx.y * COLS;

    int per = (n + SCHUNKS - 1) / SCHUNKS;
    int s0 = blockIdx.x * per;
    int s1 = min(n, s0 + per);

    int i = s0 + w;
    // 4x unroll (per-wave stride 4): batch 4 independent 256B loads for MLP.
    for (; i + 12 < s1; i += 16) {
        int la = load_label(lab, i,      is64);
        int lb = load_label(lab, i + 4,  is64);
        int lc = load_label(lab, i + 8,  is64);
        int ld = load_label(lab, i + 12, is64);
        float va = feat[(size_t)(i)      * DIM + d0 + lane];
        float vb = feat[(size_t)(i + 4)  * DIM + d0 + lane];
        float vc = feat[(size_t)(i + 8)  * DIM + d0 + lane];
        float vd = feat[(size_t)(i + 12) * DIM + d0 + lane];
        atomicAdd(&lsum[la * COLS + lane], va);
        atomicAdd(&lsum[lb * COLS + lane], vb);
        atomicAdd(&lsum[lc * COLS + lane], vc);
        atomicAdd(&lsum[ld * COLS + lane], vd);
        if (doCnt && lane == 0) {
            atomicAdd(&lcnt[la], 1.0f);
            atomicAdd(&lcnt[lb], 1.0f);
            atomicAdd(&lcnt[lc], 1.0f);
            atomicAdd(&lcnt[ld], 1.0f);
        }
    }
    for (; i < s1; i += 4) {
        int la = load_label(lab, i, is64);
        float va = feat[(size_t)i * DIM + d0 + lane];
        atomicAdd(&lsum[la * COLS + lane], va);
        if (doCnt && lane == 0) atomicAdd(&lcnt[la], 1.0f);
    }
    __syncthreads();

    // Flush LDS partials to global (L2-resident 100KB region).
    for (int idx = t; idx < NCLASS * COLS; idx += BLOCK) {
        int c = idx / COLS, d = idx % COLS;
        atomicAdd(&sums[c * DIM + d0 + d], lsum[idx]);
    }
    if (doCnt) for (int c = t; c < NCLASS; c += BLOCK) atomicAdd(&counts[c], lcnt[c]);
}

// Kernel 2: centers = sums / counts
__global__ __launch_bounds__(BLOCK) void k2_centers(const float* __restrict__ sums,
                                                    const float* __restrict__ counts,
                                                    float* __restrict__ centers) {
    int idx = blockIdx.x * BLOCK + threadIdx.x;
    if (idx < NCLASS * DIM) {
        float cnt = counts[idx / DIM];
        centers[idx] = sums[idx] / fmaxf(cnt, 1.0f);
    }
}

// Kernel 3: one wave per sample; lane l holds float4 at columns 4l..4l+3.
__global__ __launch_bounds__(BLOCK) void k3_dist(const float* __restrict__ feat,
                                                 const unsigned int* __restrict__ lab,
                                                 const int* __restrict__ flag,
                                                 const float* __restrict__ centers,
                                                 float* __restrict__ out,
                                                 int n) {
    int gw = (int)((blockIdx.x * (unsigned)BLOCK + threadIdx.x) >> 6);
    int lane = threadIdx.x & 63;
    if (gw >= n) return;
    int is64 = *flag;
    int li = load_label(lab, gw, is64);

    const float4* f = (const float4*)(feat + (size_t)gw * DIM);
    const float4* c = (const float4*)(centers + (size_t)li * DIM);
    float4 a = f[lane];
    float4 b = c[lane];
    float dx = a.x - b.x, dy = a.y - b.y, dz = a.z - b.z, dw = a.w - b.w;
    float acc = dx * dx + dy * dy + dz * dz + dw * dw;
#pragma unroll
    for (int off = 32; off > 0; off >>= 1) acc += __shfl_down(acc, off);
    if (lane == 0) out[gw] = sqrtf(acc);
}

extern "C" void kernel_launch(void* const* d_in, const int* in_sizes, int n_in,
                              void* d_out, int out_size, void* d_ws, size_t ws_size,
                              hipStream_t stream) {
    const float* feat = (const float*)d_in[0];
    const unsigned int* lab = (const unsigned int*)d_in[1];
    int n = in_sizes[0] / DIM;  // 500000

    float* ws = (float*)d_ws;
    float* sums = ws + WS_SUMS;
    float* counts = ws + WS_COUNTS;
    int* flag = (int*)(ws + WS_FLAG);
    float* centers = ws + WS_CENTERS;
    float* out = (float*)d_out;

    // k0: zero sums+counts, detect label dtype
    k0_init<<<ZERO_BLOCKS + 1, BLOCK, 0, stream>>>(ws, flag, lab, n);

    // k1: class sums + counts
    dim3 g1(SCHUNKS, NCG);
    k1_accum<<<g1, BLOCK, 0, stream>>>(feat, lab, flag, sums, counts, n);

    // k2: centers
    k2_centers<<<(NCLASS * DIM + BLOCK - 1) / BLOCK, BLOCK, 0, stream>>>(sums, counts, centers);

    // k3: per-sample distance to own center (1 wave / sample, 4 waves / block)
    int blocks = (n + 3) / 4;
    k3_dist<<<blocks, BLOCK, 0, stream>>>(feat, lab, flag, centers, out, n);
}

// Round 2
// 1253.723 us; speedup vs baseline: 1.0082x; 1.0082x over previous
//
#include <hip/hip_runtime.h>
#include <math.h>

// Problem constants (from reference): N=500000 samples, D=256 features, C=100 classes.
#define NCLASS 100
#define DIM    256

// Pass-1 tiling: 4 column-groups of 64 columns, 256 sample chunks.
#define COLS      64
#define NCG       (DIM / COLS)   // 4
#define SCHUNKS   256
#define BLOCK     256            // 4 waves

// Workspace layout (floats):
#define WS_SUMS    0
#define WS_COUNTS  (NCLASS * DIM)                  // 25600
#define WS_FLAG    (NCLASS * DIM + NCLASS)         // 25700
#define WS_CENTERS (NCLASS * DIM + NCLASS + 4)     // 25704 (float4-aligned)

#define ZERO_BLOCKS ((NCLASS * DIM + NCLASS + BLOCK - 1) / BLOCK)  // 101

// Read label i, handling both int32 and int64 (little-endian low word) layouts.
__device__ __forceinline__ int load_label(const unsigned int* lab, int i, int is64) {
    int v = is64 ? (int)lab[2 * i] : (int)lab[i];
    return min(max(v, 0), NCLASS - 1);  // clamp for memory safety
}

// Kernel 0: zero sums+counts; last block detects label dtype.
__global__ __launch_bounds__(BLOCK) void k0_init(float* __restrict__ zero_region,
                                                 int* __restrict__ flag,
                                                 const unsigned int* __restrict__ lab,
                                                 int n) {
    int b = blockIdx.x, t = threadIdx.x;
    if (b < ZERO_BLOCKS) {
        int idx = b * BLOCK + t;
        if (idx < NCLASS * DIM + NCLASS) zero_region[idx] = 0.0f;
    } else {
        __shared__ unsigned int any_nonzero;
        if (t == 0) any_nonzero = 0u;
        __syncthreads();
        unsigned int v = 0u;
        int limit = min(1024, (n - 1) / 2);
        for (int i = t; i < limit; i += BLOCK) v |= lab[2 * i + 1];
        if (v) atomicOr(&any_nonzero, 1u);
        __syncthreads();
        if (t == 0) *flag = (any_nonzero == 0u) ? 1 : 0;  // 1 => int64 layout
    }
}

// Kernel 1: accumulate class sums (LDS histogram) + counts.
// 8-sample batches per wave -> 8 outstanding 256B feat loads before the
// vmcnt drain at the LDS atomics; 1024 blocks -> 4 blocks/CU (16 waves/CU).
__global__ __launch_bounds__(BLOCK) void k1_accum(const float* __restrict__ feat,
                                                  const unsigned int* __restrict__ lab,
                                                  const int* __restrict__ flag,
                                                  float* __restrict__ sums,
                                                  float* __restrict__ counts,
                                                  int n) {
    __shared__ float lsum[NCLASS * COLS];  // 25.6 KB
    __shared__ float lcnt[NCLASS];

    int t = threadIdx.x;
    int lane = t & 63;
    int w = t >> 6;                  // wave 0..3
    bool doCnt = (blockIdx.y == 0);  // only one column-group counts

    for (int i = t; i < NCLASS * COLS; i += BLOCK) lsum[i] = 0.0f;
    if (doCnt) for (int i = t; i < NCLASS; i += BLOCK) lcnt[i] = 0.0f;
    __syncthreads();

    int is64 = *flag;
    int d0 = blockIdx.y * COLS;

    int per = (n + SCHUNKS - 1) / SCHUNKS;
    int s0 = blockIdx.x * per;
    int s1 = min(n, s0 + per);

    // wave w owns batches [s0 + w*8 + m*32, +8)
    int i = s0 + w * 8;
    for (; i + 8 <= s1; i += 32) {
        int   l[8];
        float v[8];
#pragma unroll
        for (int k = 0; k < 8; k++) l[k] = load_label(lab, i + k, is64);
#pragma unroll
        for (int k = 0; k < 8; k++) v[k] = feat[(size_t)(i + k) * DIM + d0 + lane];
#pragma unroll
        for (int k = 0; k < 8; k++) atomicAdd(&lsum[l[k] * COLS + lane], v[k]);
        if (doCnt && lane == 0) {
#pragma unroll
            for (int k = 0; k < 8; k++) atomicAdd(&lcnt[l[k]], 1.0f);
        }
    }
    // tail: partial batch for this wave
#pragma unroll 1
    for (int k = 0; k < 8; k++) {
        int ii = i + k;
        if (ii >= s1) break;
        int la = load_label(lab, ii, is64);
        float va = feat[(size_t)ii * DIM + d0 + lane];
        atomicAdd(&lsum[la * COLS + lane], va);
        if (doCnt && lane == 0) atomicAdd(&lcnt[la], 1.0f);
    }
    __syncthreads();

    // Flush LDS partials to global (L2-resident 100KB region).
    for (int idx = t; idx < NCLASS * COLS; idx += BLOCK) {
        int c = idx / COLS, d = idx % COLS;
        atomicAdd(&sums[c * DIM + d0 + d], lsum[idx]);
    }
    if (doCnt) for (int c = t; c < NCLASS; c += BLOCK) atomicAdd(&counts[c], lcnt[c]);
}

// Kernel 2: centers = sums / counts
__global__ __launch_bounds__(BLOCK) void k2_centers(const float* __restrict__ sums,
                                                    const float* __restrict__ counts,
                                                    float* __restrict__ centers) {
    int idx = blockIdx.x * BLOCK + threadIdx.x;
    if (idx < NCLASS * DIM) {
        float cnt = counts[idx / DIM];
        centers[idx] = sums[idx] / fmaxf(cnt, 1.0f);
    }
}

// Kernel 3: grid-stride, one wave per sample, 2 samples in flight per wave.
#define K3_BLOCKS 2048
__global__ __launch_bounds__(BLOCK) void k3_dist(const float* __restrict__ feat,
                                                 const unsigned int* __restrict__ lab,
                                                 const int* __restrict__ flag,
                                                 const float* __restrict__ centers,
                                                 float* __restrict__ out,
                                                 int n) {
    int wid = (int)((blockIdx.x * (unsigned)BLOCK + threadIdx.x) >> 6);
    int lane = threadIdx.x & 63;
    int nw = (K3_BLOCKS * BLOCK) >> 6;  // total waves
    int is64 = *flag;

    for (int i = wid; i < n; i += 2 * nw) {
        int j = i + nw;
        bool hasj = (j < n);  // wave-uniform

        int li = load_label(lab, i, is64);
        float4 a = ((const float4*)(feat + (size_t)i * DIM))[lane];
        int lj = 0;
        float4 c = make_float4(0.f, 0.f, 0.f, 0.f);
        if (hasj) {
            lj = load_label(lab, j, is64);
            c = ((const float4*)(feat + (size_t)j * DIM))[lane];
        }
        float4 b = ((const float4*)(centers + (size_t)li * DIM))[lane];
        float4 d = make_float4(0.f, 0.f, 0.f, 0.f);
        if (hasj) d = ((const float4*)(centers + (size_t)lj * DIM))[lane];

        float dx0 = a.x - b.x, dy0 = a.y - b.y, dz0 = a.z - b.z, dw0 = a.w - b.w;
        float acc0 = dx0 * dx0 + dy0 * dy0 + dz0 * dz0 + dw0 * dw0;
        float dx1 = c.x - d.x, dy1 = c.y - d.y, dz1 = c.z - d.z, dw1 = c.w - d.w;
        float acc1 = dx1 * dx1 + dy1 * dy1 + dz1 * dz1 + dw1 * dw1;
#pragma unroll
        for (int off = 32; off > 0; off >>= 1) {
            acc0 += __shfl_down(acc0, off);
            acc1 += __shfl_down(acc1, off);
        }
        if (lane == 0) {
            out[i] = sqrtf(acc0);
            if (hasj) out[j] = sqrtf(acc1);
        }
    }
}

extern "C" void kernel_launch(void* const* d_in, const int* in_sizes, int n_in,
                              void* d_out, int out_size, void* d_ws, size_t ws_size,
                              hipStream_t stream) {
    const float* feat = (const float*)d_in[0];
    const unsigned int* lab = (const unsigned int*)d_in[1];
    int n = in_sizes[0] / DIM;  // 500000

    float* ws = (float*)d_ws;
    float* sums = ws + WS_SUMS;
    float* counts = ws + WS_COUNTS;
    int* flag = (int*)(ws + WS_FLAG);
    float* centers = ws + WS_CENTERS;
    float* out = (float*)d_out;

    // k0: zero sums+counts, detect label dtype
    k0_init<<<ZERO_BLOCKS + 1, BLOCK, 0, stream>>>(ws, flag, lab, n);

    // k1: class sums + counts
    dim3 g1(SCHUNKS, NCG);
    k1_accum<<<g1, BLOCK, 0, stream>>>(feat, lab, flag, sums, counts, n);

    // k2: centers
    k2_centers<<<(NCLASS * DIM + BLOCK - 1) / BLOCK, BLOCK, 0, stream>>>(sums, counts, centers);

    // k3: per-sample distance to own center, grid-stride
    k3_dist<<<K3_BLOCKS, BLOCK, 0, stream>>>(feat, lab, flag, centers, out, n);
}

// Round 3
// 1027.928 us; speedup vs baseline: 1.2297x; 1.2197x over previous
//
#include <hip/hip_runtime.h>
#include <math.h>

// Problem constants (from reference): N=500000 samples, D=256 features, C=100 classes.
#define REALC  100
#define NCLASS 104               // padded to 13 groups of 8 (classes 100..103 never match)
#define DIM    256
#define CGS    8                 // classes per wave (register accumulators / centers)
#define NGRP   (NCLASS / CGS)    // 13
#define NCHUNK 512               // label chunks
#define BLOCK  256               // 4 waves

// Workspace layout (floats), total ~213 KB:
#define WS_SUMS    0
#define WS_COUNTS  (NCLASS * DIM)                  // 26624
#define WS_FLAG    (NCLASS * DIM + NCLASS)         // 26728
#define WS_CENTERS (NCLASS * DIM + NCLASS + 4)     // 26732 (x4B = 106928, 16B-aligned)

#define ZERO_N      (NCLASS * DIM + NCLASS)        // sums + counts
#define ZERO_BLOCKS ((ZERO_N + BLOCK - 1) / BLOCK) // 105

// Kernel 0: zero sums+counts; last block detects label dtype (int32 vs int64).
__global__ __launch_bounds__(BLOCK) void k0_init(float* __restrict__ zero_region,
                                                 int* __restrict__ flag,
                                                 const unsigned int* __restrict__ lab,
                                                 int n) {
    int b = blockIdx.x, t = threadIdx.x;
    if (b < ZERO_BLOCKS) {
        int idx = b * BLOCK + t;
        if (idx < ZERO_N) zero_region[idx] = 0.0f;
    } else {
        // int64 labels (<100) have zero high words at odd int32 slots.
        __shared__ unsigned int any_nonzero;
        if (t == 0) any_nonzero = 0u;
        __syncthreads();
        unsigned int v = 0u;
        int limit = min(1024, (n - 1) / 2);
        for (int i = t; i < limit; i += BLOCK) v |= lab[2 * i + 1];
        if (v) atomicOr(&any_nonzero, 1u);
        __syncthreads();
        if (t == 0) *flag = (any_nonzero == 0u) ? 1 : 0;  // 1 => int64 layout
    }
}

// Per-lane label load; OOB lanes get a sentinel that matches no class.
__device__ __forceinline__ int load_label_lane(const unsigned int* lab, int idx, int s1, int is64) {
    if (idx >= s1) return 0x7fffffff;
    return is64 ? (int)lab[2 * (size_t)idx] : (int)lab[idx];
}

// Kernel 1 (class-gather): wave = (8-class group, label chunk).
// Scan 64 labels/step -> 8 ballots -> for each match load the full 1KB row
// (float4/lane) and accumulate into register float4 acc[8]. No atomics in the
// hot loop; counts from ballot popcounts.
__global__ __launch_bounds__(BLOCK, 6) void k1_accum(const float* __restrict__ feat,
                                                     const unsigned int* __restrict__ lab,
                                                     const int* __restrict__ flag,
                                                     float* __restrict__ sums,
                                                     float* __restrict__ counts,
                                                     int n) {
    __shared__ float lsum[CGS * DIM];  // 8 KB

    int t = threadIdx.x, lane = t & 63, w = t >> 6;
    int c0 = blockIdx.y * CGS;
    int chunk = blockIdx.x * 4 + w;
    int CH = (n + NCHUNK - 1) / NCHUNK;
    int s0 = chunk * CH, s1 = min(n, s0 + CH);
    int is64 = *flag;

    float4 acc[CGS];
    int cnt[CGS];
#pragma unroll
    for (int k = 0; k < CGS; k++) {
        acc[k] = make_float4(0.f, 0.f, 0.f, 0.f);
        cnt[k] = 0;
    }

    for (int base = s0; base < s1; base += 64) {
        int lv = load_label_lane(lab, base + lane, s1, is64);
        unsigned long long m[CGS], um = 0ull;
#pragma unroll
        for (int k = 0; k < CGS; k++) {
            m[k] = __ballot(lv == c0 + k);
            um |= m[k];
            cnt[k] += (int)__popcll(m[k]);
        }
        while (um) {
            int b = __ffsll((unsigned long long)um) - 1;
            um &= um - 1ull;
            float4 r = ((const float4*)(feat + (size_t)(base + b) * DIM))[lane];
#pragma unroll
            for (int k = 0; k < CGS; k++)
                if ((m[k] >> b) & 1ull) {
                    acc[k].x += r.x; acc[k].y += r.y; acc[k].z += r.z; acc[k].w += r.w;
                }
        }
    }

    // Combine the block's 4 waves in LDS, then one global atomic per element.
    for (int i = t; i < CGS * DIM; i += BLOCK) lsum[i] = 0.0f;
    __syncthreads();
#pragma unroll
    for (int k = 0; k < CGS; k++) {
        atomicAdd(&lsum[k * DIM + 4 * lane + 0], acc[k].x);
        atomicAdd(&lsum[k * DIM + 4 * lane + 1], acc[k].y);
        atomicAdd(&lsum[k * DIM + 4 * lane + 2], acc[k].z);
        atomicAdd(&lsum[k * DIM + 4 * lane + 3], acc[k].w);
    }
    __syncthreads();
    for (int i = t; i < CGS * DIM; i += BLOCK) {
        int k = i >> 8, col = i & 255;
        atomicAdd(&sums[(size_t)(c0 + k) * DIM + col], lsum[i]);
    }
    if (lane == 0) {
#pragma unroll
        for (int k = 0; k < CGS; k++)
            if (cnt[k]) atomicAdd(&counts[c0 + k], (float)cnt[k]);
    }
}

// Kernel 2: centers = sums / counts (padded classes -> 0, never matched anyway)
__global__ __launch_bounds__(BLOCK) void k2_centers(const float* __restrict__ sums,
                                                    const float* __restrict__ counts,
                                                    float* __restrict__ centers) {
    int idx = blockIdx.x * BLOCK + threadIdx.x;
    if (idx < NCLASS * DIM) {
        float cnt = counts[idx / DIM];
        centers[idx] = sums[idx] / fmaxf(cnt, 1.0f);
    }
}

// Kernel 3 (class-gather): wave = (8-class group, label chunk). Preload the 8
// class centers into registers once; per matched row: load row, subtract the
// register center, shfl-reduce, store distance. No per-sample gathers.
__global__ __launch_bounds__(BLOCK, 6) void k3_dist(const float* __restrict__ feat,
                                                    const unsigned int* __restrict__ lab,
                                                    const int* __restrict__ flag,
                                                    const float* __restrict__ centers,
                                                    float* __restrict__ out,
                                                    int n) {
    int t = threadIdx.x, lane = t & 63, w = t >> 6;
    int c0 = blockIdx.y * CGS;
    int chunk = blockIdx.x * 4 + w;
    int CH = (n + NCHUNK - 1) / NCHUNK;
    int s0 = chunk * CH, s1 = min(n, s0 + CH);
    int is64 = *flag;

    float4 ctr[CGS];
#pragma unroll
    for (int k = 0; k < CGS; k++)
        ctr[k] = ((const float4*)(centers + (size_t)(c0 + k) * DIM))[lane];

    for (int base = s0; base < s1; base += 64) {
        int lv = load_label_lane(lab, base + lane, s1, is64);
        unsigned long long m[CGS], um = 0ull;
#pragma unroll
        for (int k = 0; k < CGS; k++) {
            m[k] = __ballot(lv == c0 + k);
            um |= m[k];
        }
        while (um) {
            int b = __ffsll((unsigned long long)um) - 1;
            um &= um - 1ull;
            int row = base + b;
            float4 r = ((const float4*)(feat + (size_t)row * DIM))[lane];
            float4 c = ctr[0];
#pragma unroll
            for (int k = 1; k < CGS; k++)
                if ((m[k] >> b) & 1ull) c = ctr[k];
            float dx = r.x - c.x, dy = r.y - c.y, dz = r.z - c.z, dw = r.w - c.w;
            float p = dx * dx + dy * dy + dz * dz + dw * dw;
#pragma unroll
            for (int off = 32; off > 0; off >>= 1) p += __shfl_down(p, off);
            if (lane == 0) out[row] = sqrtf(p);
        }
    }
}

extern "C" void kernel_launch(void* const* d_in, const int* in_sizes, int n_in,
                              void* d_out, int out_size, void* d_ws, size_t ws_size,
                              hipStream_t stream) {
    const float* feat = (const float*)d_in[0];
    const unsigned int* lab = (const unsigned int*)d_in[1];
    int n = in_sizes[0] / DIM;  // 500000

    float* ws = (float*)d_ws;
    float* sums = ws + WS_SUMS;
    float* counts = ws + WS_COUNTS;
    int* flag = (int*)(ws + WS_FLAG);
    float* centers = ws + WS_CENTERS;
    float* out = (float*)d_out;

    // k0: zero sums+counts, detect label dtype
    k0_init<<<ZERO_BLOCKS + 1, BLOCK, 0, stream>>>(ws, flag, lab, n);

    // k1: class sums + counts (class-gather)
    dim3 g1(NCHUNK / 4, NGRP);  // (128, 13) = 1664 blocks
    k1_accum<<<g1, BLOCK, 0, stream>>>(feat, lab, flag, sums, counts, n);

    // k2: centers
    k2_centers<<<(NCLASS * DIM + BLOCK - 1) / BLOCK, BLOCK, 0, stream>>>(sums, counts, centers);

    // k3: distances (class-gather, register centers)
    dim3 g3(NCHUNK / 4, NGRP);
    k3_dist<<<g3, BLOCK, 0, stream>>>(feat, lab, flag, centers, out, n);
}